// Round 3
// baseline (248.127 us; speedup 1.0000x reference)
//
#include <hip/hip_runtime.h>
#include <hip/hip_fp16.h>

// ---------- types ----------
typedef __attribute__((ext_vector_type(8))) _Float16 f16x8;
typedef __attribute__((ext_vector_type(4))) float f32x4;

#define LDS_K 72   // 64 + 8 pad: 144B row stride breaks power-of-2 bank aliasing

// ---------- cast f32 -> f16 ----------
__global__ __launch_bounds__(256) void cast_f32_f16_k(const float* __restrict__ in,
                                                      __half* __restrict__ out, int n) {
    int i = (blockIdx.x * 256 + threadIdx.x) * 8;
    if (i >= n) return;
    float4 a = *(const float4*)(in + i);
    float4 b = *(const float4*)(in + i + 4);
    __half2 h[4] = { __floats2half2_rn(a.x, a.y), __floats2half2_rn(a.z, a.w),
                     __floats2half2_rn(b.x, b.y), __floats2half2_rn(b.z, b.w) };
    *(int4*)(out + i) = *(int4*)h;
}

// ---------- transpose [R][C] -> [C][R] (f16) ----------
__global__ __launch_bounds__(256) void transpose_f16_k(const __half* __restrict__ in,
                                                       __half* __restrict__ out, int R, int Cc) {
    __shared__ __half t[64][72];
    int r0 = blockIdx.x * 64, c0 = blockIdx.y * 64;
    for (int idx = threadIdx.x; idx < 64 * 64; idx += 256) {
        int r = idx >> 6, c = idx & 63;
        t[r][c] = in[(size_t)(r0 + r) * Cc + c0 + c];
    }
    __syncthreads();
    for (int idx = threadIdx.x; idx < 64 * 64; idx += 256) {
        int r = idx >> 6, c = idx & 63;
        out[(size_t)(c0 + r) * R + r0 + c] = t[c][r];
    }
}

// ---------- GEMM C[M][N] = scale * A[M][K] @ B[N][K]^T  (NT, f16 in, MFMA) ----------
__device__ __forceinline__ void storeC(__half* C, size_t off, float v) { C[off] = __float2half(v); }
__device__ __forceinline__ void storeC(float*  C, size_t off, float v) { C[off] = v; }

template <typename CT, bool LOWER_ONLY, bool DIAG_KLIM>
__global__ __launch_bounds__(256, 2)
void gemm_nt(const __half* __restrict__ A, const __half* __restrict__ B, CT* __restrict__ C,
             int M, int N, int Kd, int lda, int ldb, int ldc, float scale) {
    const int bi = blockIdx.x, bj = blockIdx.y;
    if (LOWER_ONLY && bj > bi) return;
    const int brow = bi * 128, bcol = bj * 128;
    const int tid = threadIdx.x, lane = tid & 63, wid = tid >> 6;
    const int wr = (wid >> 1) * 64, wc = (wid & 1) * 64;

    __shared__ __align__(16) __half As[128 * LDS_K];
    __shared__ __align__(16) __half Bs[128 * LDS_K];

    f32x4 acc[4][4] = {};

    int kmax = Kd;
    if (DIAG_KLIM) kmax = min(Kd, brow + 128);
    const int nk = kmax >> 6;  // BK = 64

    for (int kt = 0; kt < nk; ++kt) {
        const int k0 = kt << 6;
#pragma unroll
        for (int it = 0; it < 4; ++it) {
            int c  = it * 256 + tid;
            int r  = c >> 3, kc = (c & 7) << 3;
            *(int4*)(&As[r * LDS_K + kc]) = *(const int4*)(A + (size_t)(brow + r) * lda + k0 + kc);
            *(int4*)(&Bs[r * LDS_K + kc]) = *(const int4*)(B + (size_t)(bcol + r) * ldb + k0 + kc);
        }
        __syncthreads();
#pragma unroll
        for (int kk = 0; kk < 2; ++kk) {
            const int ko = kk * 32 + ((lane >> 4) << 3);
            f16x8 af[4], bf[4];
#pragma unroll
            for (int m = 0; m < 4; ++m)
                af[m] = *(const f16x8*)(&As[(wr + m * 16 + (lane & 15)) * LDS_K + ko]);
#pragma unroll
            for (int n = 0; n < 4; ++n)
                bf[n] = *(const f16x8*)(&Bs[(wc + n * 16 + (lane & 15)) * LDS_K + ko]);
#pragma unroll
            for (int m = 0; m < 4; ++m)
#pragma unroll
                for (int n = 0; n < 4; ++n)
                    acc[m][n] = __builtin_amdgcn_mfma_f32_16x16x32_f16(af[m], bf[n], acc[m][n], 0, 0, 0);
        }
        __syncthreads();
    }

    const int r0 = (lane >> 4) << 2;
    const int cc = lane & 15;
#pragma unroll
    for (int m = 0; m < 4; ++m) {
#pragma unroll
        for (int n = 0; n < 4; ++n) {
            int col = bcol + wc + n * 16 + cc;
#pragma unroll
            for (int r = 0; r < 4; ++r) {
                int row = brow + wr + m * 16 + r0 + r;
                storeC(C, (size_t)row * ldc + col, acc[m][n][r] * scale);
            }
        }
    }
}

// ---------- threefry2x32, JAX PARTITIONABLE variant (default since jax 0.4.30) ----------
// bits[f] = y0 ^ y1 of threefry2x32(key=(0,42), counts=(hi32(f)=0, lo32(f)=f))
__device__ __forceinline__ uint32_t rotl32(uint32_t x, int d) { return (x << d) | (x >> (32 - d)); }

__device__ __forceinline__ bool keep_bit(uint32_t i, uint32_t j) {
    uint32_t x0 = 0u;
    uint32_t x1 = i * 4096u + j;
    const uint32_t ks0 = 0u, ks1 = 42u, ks2 = 0u ^ 42u ^ 0x1BD11BDAu;
    x0 += ks0; x1 += ks1;
#define TFR(r) { x0 += x1; x1 = rotl32(x1, r); x1 ^= x0; }
    TFR(13) TFR(15) TFR(26) TFR(6)   x0 += ks1; x1 += ks2 + 1u;
    TFR(17) TFR(29) TFR(16) TFR(24)  x0 += ks2; x1 += ks0 + 2u;
    TFR(13) TFR(15) TFR(26) TFR(6)   x0 += ks0; x1 += ks1 + 3u;
    TFR(17) TFR(29) TFR(16) TFR(24)  x0 += ks1; x1 += ks2 + 4u;
    TFR(13) TFR(15) TFR(26) TFR(6)   x0 += ks2; x1 += ks0 + 5u;
#undef TFR
    uint32_t bits = x0 ^ x1;
    float u = __uint_as_float((bits >> 9) | 0x3f800000u) - 1.0f;
    return u < 0.9f;
}

// ---------- row softmax + dropout, in-place S(f16) -> P(f16) ----------
__global__ __launch_bounds__(256) void softmax_dropout_k(__half* __restrict__ SP, int N) {
    const int i = blockIdx.x;
    const int tid = threadIdx.x;
    const int len = i + 1;
    __half* row = SP + (size_t)i * N;

    float m = -1.0e30f, l = 0.f;
    for (int j = tid; j < len; j += 256) {
        float s = __half2float(row[j]);
        float nm = fmaxf(m, s);
        l = l * __expf(m - nm) + __expf(s - nm);
        m = nm;
    }
    for (int off = 1; off < 64; off <<= 1) {
        float m2 = __shfl_xor(m, off);
        float l2 = __shfl_xor(l, off);
        float nm = fmaxf(m, m2);
        l = l * __expf(m - nm) + l2 * __expf(m2 - nm);
        m = nm;
    }
    __shared__ float ms[4], ls[4];
    if ((tid & 63) == 0) { ms[tid >> 6] = m; ls[tid >> 6] = l; }
    __syncthreads();
    float M = ms[0], L = ls[0];
#pragma unroll
    for (int w = 1; w < 4; ++w) {
        float nm = fmaxf(M, ms[w]);
        L = L * __expf(M - nm) + ls[w] * __expf(ms[w] - nm);
        M = nm;
    }
    const float inv = 1.0f / (L * 0.9f);

    for (int j = tid; j < len; j += 256) {
        float s = __half2float(row[j]);
        float w = __expf(s - M) * inv;
        row[j] = keep_bit((uint32_t)i, (uint32_t)j) ? __float2half(w) : __float2half(0.0f);
    }
    for (int j = len + tid; j < N; j += 256) row[j] = __float2half(0.0f);
}

// ---------- launch ----------
extern "C" void kernel_launch(void* const* d_in, const int* in_sizes, int n_in,
                              void* d_out, int out_size, void* d_ws, size_t ws_size,
                              hipStream_t stream) {
    const float* x  = (const float*)d_in[0];
    const float* wq = (const float*)d_in[1];
    const float* wk = (const float*)d_in[2];
    const float* wv = (const float*)d_in[3];
    float* out = (float*)d_out;
    char* ws = (char*)d_ws;

    const int N = 4096, D = 1024;

    __half* xb  = (__half*)(ws + 0);                       // 4096x1024
    __half* wqb = (__half*)(ws + 8388608);                 // 1024x1024
    __half* wkb = (__half*)(ws + 10485760);
    __half* wvb = (__half*)(ws + 12582912);
    __half* Q   = (__half*)(ws + 14680064);                // 4096x1024
    __half* Km  = (__half*)(ws + 23068672);
    __half* V   = (__half*)(ws + 31457280);
    __half* VT  = (__half*)(ws + 39845888);                // 1024x4096
    __half* SP  = (__half*)(ws + 48234496);                // 4096x4096 (S then P, in place)

    cast_f32_f16_k<<<2048, 256, 0, stream>>>(x,  xb,  N * D);
    cast_f32_f16_k<<<512,  256, 0, stream>>>(wq, wqb, D * D);
    cast_f32_f16_k<<<512,  256, 0, stream>>>(wk, wkb, D * D);
    cast_f32_f16_k<<<512,  256, 0, stream>>>(wv, wvb, D * D);

    dim3 gq(N / 128, D / 128);  // 32 x 8
    gemm_nt<__half, false, false><<<gq, 256, 0, stream>>>(xb, wqb, Q,  N, D, D, D, D, D, 1.0f);
    gemm_nt<__half, false, false><<<gq, 256, 0, stream>>>(xb, wkb, Km, N, D, D, D, D, D, 1.0f);
    gemm_nt<__half, false, false><<<gq, 256, 0, stream>>>(xb, wvb, V,  N, D, D, D, D, D, 1.0f);

    dim3 gt(N / 64, D / 64);    // 64 x 16
    transpose_f16_k<<<gt, 256, 0, stream>>>(V, VT, N, D);

    dim3 gs(N / 128, N / 128);  // 32 x 32, lower-only
    gemm_nt<__half, true, false><<<gs, 256, 0, stream>>>(Q, Km, SP, N, N, D, D, D, N, 0.03125f);

    softmax_dropout_k<<<N, 256, 0, stream>>>(SP, N);

    dim3 go(N / 128, D / 128);  // 32 x 8, K limited to diagonal
    gemm_nt<float, false, true><<<go, 256, 0, stream>>>(SP, VT, out, N, D, N, N, N, D, 1.0f);
}

// Round 4
// 231.979 us; speedup vs baseline: 1.0696x; 1.0696x over previous
//
#include <hip/hip_runtime.h>
#include <hip/hip_fp16.h>

// ---------- types ----------
typedef __attribute__((ext_vector_type(8))) _Float16 f16x8;
typedef __attribute__((ext_vector_type(4))) float f32x4;

typedef const __attribute__((address_space(1))) void gas_void;
typedef __attribute__((address_space(3))) void las_void;

// ---------- cast f32 -> f16 ----------
__global__ __launch_bounds__(256) void cast_f32_f16_k(const float* __restrict__ in,
                                                      __half* __restrict__ out, int n) {
    int i = (blockIdx.x * 256 + threadIdx.x) * 8;
    if (i >= n) return;
    float4 a = *(const float4*)(in + i);
    float4 b = *(const float4*)(in + i + 4);
    __half2 h[4] = { __floats2half2_rn(a.x, a.y), __floats2half2_rn(a.z, a.w),
                     __floats2half2_rn(b.x, b.y), __floats2half2_rn(b.z, b.w) };
    *(int4*)(out + i) = *(int4*)h;
}

// ---------- transpose [R][C] (row stride ldin) -> [C][R] (f16) ----------
__global__ __launch_bounds__(256) void transpose_f16_k(const __half* __restrict__ in,
                                                       __half* __restrict__ out,
                                                       int R, int ldin) {
    __shared__ __half t[64][72];
    int r0 = blockIdx.x * 64, c0 = blockIdx.y * 64;
    for (int idx = threadIdx.x; idx < 64 * 64; idx += 256) {
        int r = idx >> 6, c = idx & 63;
        t[r][c] = in[(size_t)(r0 + r) * ldin + c0 + c];
    }
    __syncthreads();
    for (int idx = threadIdx.x; idx < 64 * 64; idx += 256) {
        int r = idx >> 6, c = idx & 63;
        out[(size_t)(c0 + r) * R + r0 + c] = t[c][r];
    }
}

// ---------- GEMM C[M][N] = scale * A[M][K] @ B[N][K]^T  (NT, f16, MFMA, gload_lds) ----------
// m97 structure: 128x128 tile, BK=64, 4 waves, LINEAR LDS [128][64], global_load_lds width=16.
__device__ __forceinline__ void storeC(__half* C, size_t off, float v) { C[off] = __float2half(v); }
__device__ __forceinline__ void storeC(float*  C, size_t off, float v) { C[off] = v; }

template <typename CT, bool LOWER_ONLY, bool DIAG_KLIM>
__global__ __launch_bounds__(256)
void gemm_nt(const __half* __restrict__ A, const __half* __restrict__ B, CT* __restrict__ C,
             int M, int N, int Kd, int lda, int ldb, int ldc, float scale) {
    const int bi = blockIdx.x, bj = blockIdx.y;
    if (LOWER_ONLY && bj > bi) return;
    const int brow = bi * 128, bcol = bj * 128;
    const int tid = threadIdx.x, lane = tid & 63, wid = tid >> 6;
    const int wr = (wid >> 1) * 64, wc = (wid & 1) * 64;

    __shared__ __align__(16) __half As[128 * 64];
    __shared__ __align__(16) __half Bs[128 * 64];

    f32x4 acc[4][4] = {};

    // staging: wave w owns rows [w*32, w*32+32); lane l -> row +(l>>3), halves (l&7)*8.
    // LDS dest: wave-uniform base + lane*16 (linear [row][64] layout). [m97 pattern]
    const int srow = (wid << 5) + (lane >> 3);
    const int skc  = (lane & 7) << 3;
    const __half* Ag = A + (size_t)(brow + srow) * lda + skc;
    const __half* Bg = B + (size_t)(bcol + srow) * ldb + skc;

    int kmax = Kd;
    if (DIAG_KLIM) kmax = min(Kd, brow + 128);
    const int nk = kmax >> 6;  // BK = 64

    for (int kt = 0; kt < nk; ++kt) {
        const int k0 = kt << 6;
#pragma unroll
        for (int it = 0; it < 4; ++it) {
            __builtin_amdgcn_global_load_lds(
                (gas_void*)(Ag + (size_t)it * 8 * lda + k0),
                (las_void*)(&As[((wid << 5) + it * 8) * 64]), 16, 0, 0);
            __builtin_amdgcn_global_load_lds(
                (gas_void*)(Bg + (size_t)it * 8 * ldb + k0),
                (las_void*)(&Bs[((wid << 5) + it * 8) * 64]), 16, 0, 0);
        }
        __syncthreads();
#pragma unroll
        for (int kk = 0; kk < 2; ++kk) {
            const int ko = kk * 32 + ((lane >> 4) << 3);
            f16x8 af[4], bf[4];
#pragma unroll
            for (int m = 0; m < 4; ++m)
                af[m] = *(const f16x8*)(&As[(wr + m * 16 + (lane & 15)) * 64 + ko]);
#pragma unroll
            for (int n = 0; n < 4; ++n)
                bf[n] = *(const f16x8*)(&Bs[(wc + n * 16 + (lane & 15)) * 64 + ko]);
#pragma unroll
            for (int m = 0; m < 4; ++m)
#pragma unroll
                for (int n = 0; n < 4; ++n)
                    acc[m][n] = __builtin_amdgcn_mfma_f32_16x16x32_f16(af[m], bf[n], acc[m][n], 0, 0, 0);
        }
        __syncthreads();
    }

    const int r0 = (lane >> 4) << 2;
    const int cc = lane & 15;
#pragma unroll
    for (int m = 0; m < 4; ++m) {
#pragma unroll
        for (int n = 0; n < 4; ++n) {
            int col = bcol + wc + n * 16 + cc;
#pragma unroll
            for (int r = 0; r < 4; ++r) {
                int row = brow + wr + m * 16 + r0 + r;
                storeC(C, (size_t)row * ldc + col, acc[m][n][r] * scale);
            }
        }
    }
}

// ---------- threefry2x32, JAX PARTITIONABLE variant ----------
__device__ __forceinline__ uint32_t rotl32(uint32_t x, int d) { return (x << d) | (x >> (32 - d)); }

__device__ __forceinline__ bool keep_bit(uint32_t i, uint32_t j) {
    uint32_t x0 = 0u;
    uint32_t x1 = i * 4096u + j;
    const uint32_t ks0 = 0u, ks1 = 42u, ks2 = 0u ^ 42u ^ 0x1BD11BDAu;
    x0 += ks0; x1 += ks1;
#define TFR(r) { x0 += x1; x1 = rotl32(x1, r); x1 ^= x0; }
    TFR(13) TFR(15) TFR(26) TFR(6)   x0 += ks1; x1 += ks2 + 1u;
    TFR(17) TFR(29) TFR(16) TFR(24)  x0 += ks2; x1 += ks0 + 2u;
    TFR(13) TFR(15) TFR(26) TFR(6)   x0 += ks0; x1 += ks1 + 3u;
    TFR(17) TFR(29) TFR(16) TFR(24)  x0 += ks1; x1 += ks2 + 4u;
    TFR(13) TFR(15) TFR(26) TFR(6)   x0 += ks2; x1 += ks0 + 5u;
#undef TFR
    uint32_t bits = x0 ^ x1;
    float u = __uint_as_float((bits >> 9) | 0x3f800000u) - 1.0f;
    return u < 0.9f;
}

// ---------- row softmax + dropout, in-place S(f16) -> P(f16) ----------
__global__ __launch_bounds__(256) void softmax_dropout_k(__half* __restrict__ SP, int N) {
    const int i = blockIdx.x;
    const int tid = threadIdx.x;
    const int len = i + 1;
    __half* row = SP + (size_t)i * N;

    // pass 1: online max/sum, vectorized 8-wide
    float m = -1.0e30f, l = 0.f;
    const int len8 = len & ~7;
    for (int j = tid * 8; j < len8; j += 2048) {
        int4 pk = *(const int4*)(row + j);
        const __half2* h2 = (const __half2*)&pk;
#pragma unroll
        for (int q = 0; q < 4; ++q) {
            float2 f2 = __half22float2(h2[q]);
            float nm = fmaxf(m, fmaxf(f2.x, f2.y));
            l = l * __expf(m - nm) + __expf(f2.x - nm) + __expf(f2.y - nm);
            m = nm;
        }
    }
    for (int j = len8 + tid; j < len; j += 256) {
        float s = __half2float(row[j]);
        float nm = fmaxf(m, s);
        l = l * __expf(m - nm) + __expf(s - nm);
        m = nm;
    }
    for (int off = 1; off < 64; off <<= 1) {
        float m2 = __shfl_xor(m, off);
        float l2 = __shfl_xor(l, off);
        float nm = fmaxf(m, m2);
        l = l * __expf(m - nm) + l2 * __expf(m2 - nm);
        m = nm;
    }
    __shared__ float ms[4], ls[4];
    if ((tid & 63) == 0) { ms[tid >> 6] = m; ls[tid >> 6] = l; }
    __syncthreads();
    float M = ms[0], L = ls[0];
#pragma unroll
    for (int w = 1; w < 4; ++w) {
        float nm = fmaxf(M, ms[w]);
        L = L * __expf(M - nm) + ls[w] * __expf(ms[w] - nm);
        M = nm;
    }
    const float inv = 1.0f / (L * 0.9f);

    // pass 2: weights + dropout (threefry-bound, scalar)
    for (int j = tid; j < len; j += 256) {
        float s = __half2float(row[j]);
        float w = __expf(s - M) * inv;
        row[j] = keep_bit((uint32_t)i, (uint32_t)j) ? __float2half(w) : __float2half(0.0f);
    }
    // pass 3: zero upper triangle, vectorized
    const int z0 = (len + 7) & ~7;
    for (int j = len + tid; j < min(z0, N); j += 256) row[j] = __float2half(0.0f);
    for (int j = z0 + tid * 8; j < N; j += 2048) {
        int4 z = {0, 0, 0, 0};
        *(int4*)(row + j) = z;
    }
}

// ---------- launch ----------
extern "C" void kernel_launch(void* const* d_in, const int* in_sizes, int n_in,
                              void* d_out, int out_size, void* d_ws, size_t ws_size,
                              hipStream_t stream) {
    const float* x  = (const float*)d_in[0];
    const float* wq = (const float*)d_in[1];
    const float* wk = (const float*)d_in[2];
    const float* wv = (const float*)d_in[3];
    float* out = (float*)d_out;
    char* ws = (char*)d_ws;

    const int N = 4096, D = 1024;

    __half* xb   = (__half*)(ws + 0);         // 4096x1024   (8 MB)
    __half* wqkv = (__half*)(ws + 8388608);   // 3072x1024   (6 MB) — wq,wk,wv stacked
    __half* QKV  = (__half*)(ws + 14680064);  // 4096x3072   (24 MB) — Q|K|V interleaved, ld=3072
    __half* VT   = (__half*)(ws + 39845888);  // 1024x4096   (8 MB)
    __half* SP   = (__half*)(ws + 48234496);  // 4096x4096   (32 MB), end = 81788928

    __half* Q = QKV;            // lda = 3072
    __half* K = QKV + 1024;
    __half* V = QKV + 2048;

    cast_f32_f16_k<<<2048, 256, 0, stream>>>(x,  xb,  N * D);
    cast_f32_f16_k<<<512,  256, 0, stream>>>(wq, wqkv,            D * D);
    cast_f32_f16_k<<<512,  256, 0, stream>>>(wk, wqkv + D * D,    D * D);
    cast_f32_f16_k<<<512,  256, 0, stream>>>(wv, wqkv + 2 * D * D, D * D);

    // fused QKV projection: [4096x1024] @ [3072x1024]^T -> [4096x3072]
    dim3 gq(N / 128, 3 * D / 128);  // 32 x 24 = 768 blocks
    gemm_nt<__half, false, false><<<gq, 256, 0, stream>>>(xb, wqkv, QKV, N, 3 * D, D, D, D, 3 * D, 1.0f);

    dim3 gt(N / 64, D / 64);        // 64 x 16
    transpose_f16_k<<<gt, 256, 0, stream>>>(V, VT, N, 3 * D);

    dim3 gs(N / 128, N / 128);      // 32 x 32, lower-only
    gemm_nt<__half, true, false><<<gs, 256, 0, stream>>>(Q, K, SP, N, N, D, 3 * D, 3 * D, N, 0.03125f);

    softmax_dropout_k<<<N, 256, 0, stream>>>(SP, N);

    dim3 go(N / 128, D / 128);      // 32 x 8, K limited to diagonal
    gemm_nt<float, false, true><<<go, 256, 0, stream>>>(SP, VT, out, N, D, N, N, N, D, 1.0f);
}

// Round 5
// 205.162 us; speedup vs baseline: 1.2094x; 1.1307x over previous
//
#include <hip/hip_runtime.h>
#include <hip/hip_fp16.h>

// ---------- types ----------
typedef __attribute__((ext_vector_type(8))) _Float16 f16x8;
typedef __attribute__((ext_vector_type(4))) float f32x4;

typedef const __attribute__((address_space(1))) void gas_void;
typedef __attribute__((address_space(3))) void las_void;

// ---------- cast f32 -> f16 ----------
__global__ __launch_bounds__(256) void cast_f32_f16_k(const float* __restrict__ in,
                                                      __half* __restrict__ out, int n) {
    int i = (blockIdx.x * 256 + threadIdx.x) * 8;
    if (i >= n) return;
    float4 a = *(const float4*)(in + i);
    float4 b = *(const float4*)(in + i + 4);
    __half2 h[4] = { __floats2half2_rn(a.x, a.y), __floats2half2_rn(a.z, a.w),
                     __floats2half2_rn(b.x, b.y), __floats2half2_rn(b.z, b.w) };
    *(int4*)(out + i) = *(int4*)h;
}

// ---------- transpose [R][C] (row stride ldin) -> [C][R] (f16) ----------
__global__ __launch_bounds__(256) void transpose_f16_k(const __half* __restrict__ in,
                                                       __half* __restrict__ out,
                                                       int R, int ldin) {
    __shared__ __half t[64][72];
    int r0 = blockIdx.x * 64, c0 = blockIdx.y * 64;
    for (int idx = threadIdx.x; idx < 64 * 64; idx += 256) {
        int r = idx >> 6, c = idx & 63;
        t[r][c] = in[(size_t)(r0 + r) * ldin + c0 + c];
    }
    __syncthreads();
    for (int idx = threadIdx.x; idx < 64 * 64; idx += 256) {
        int r = idx >> 6, c = idx & 63;
        out[(size_t)(c0 + r) * R + r0 + c] = t[c][r];
    }
}

// ---------- GEMM C = scale * A @ B^T, 128x128 tile, BK=64, dbuf LDS + gload_lds ----------
__device__ __forceinline__ void storeC(__half* C, size_t off, float v) { C[off] = __float2half(v); }
__device__ __forceinline__ void storeC(float*  C, size_t off, float v) { C[off] = v; }

__device__ __forceinline__ void stage_tile(const __half* Ag, const __half* Bg, int lda, int ldb,
                                           __half* As, __half* Bs, int wid, int k0) {
#pragma unroll
    for (int it = 0; it < 4; ++it) {
        __builtin_amdgcn_global_load_lds(
            (gas_void*)(Ag + (size_t)it * 8 * lda + k0),
            (las_void*)(&As[((wid << 5) + it * 8) * 64]), 16, 0, 0);
        __builtin_amdgcn_global_load_lds(
            (gas_void*)(Bg + (size_t)it * 8 * ldb + k0),
            (las_void*)(&Bs[((wid << 5) + it * 8) * 64]), 16, 0, 0);
    }
}

// MODE: SPLITK=false -> grid (M/128, N/128), optional LOWER_ONLY triangle skip.
//       SPLITK=true  -> grid (80, N/128): balanced causal split-K chunks of <=16 iters.
template <typename CT, bool LOWER_ONLY, bool SPLITK>
__global__ __launch_bounds__(256)
void gemm_nt(const __half* __restrict__ A, const __half* __restrict__ B, CT* __restrict__ C,
             float* __restrict__ P1, float* __restrict__ P2, float* __restrict__ P3,
             int Kd, int lda, int ldb, int ldc, float scale) {
    int bi, c = 0;
    const int bj = blockIdx.y;
    if (SPLITK) {
        int x = blockIdx.x;
        if (x < 8)       { bi = x;                 c = 0; }
        else if (x < 24) { bi = 8  + ((x - 8) >> 1);  c = (x - 8) & 1; }
        else if (x < 48) { bi = 16 + (x - 24) / 3;    c = (x - 24) % 3; }
        else             { bi = 24 + ((x - 48) >> 2); c = (x - 48) & 3; }
    } else {
        bi = blockIdx.x;
        if (LOWER_ONLY && bj > bi) return;
    }
    const int brow = bi * 128, bcol = bj * 128;
    const int tid = threadIdx.x, lane = tid & 63, wid = tid >> 6;
    const int wr = (wid >> 1) * 64, wc = (wid & 1) * 64;

    int k_lo = 0, k_hi = Kd >> 6;
    if (SPLITK) { int full = 2 * (bi + 1); k_lo = c * 16; k_hi = min(full, k_lo + 16); }

    __shared__ __align__(16) __half As[2][128 * 64];
    __shared__ __align__(16) __half Bs[2][128 * 64];

    f32x4 acc[4][4] = {};

    const int srow = (wid << 5) + (lane >> 3);
    const int skc  = (lane & 7) << 3;
    const __half* Ag = A + (size_t)(brow + srow) * lda + skc;
    const __half* Bg = B + (size_t)(bcol + srow) * ldb + skc;

    int cur = 0;
    stage_tile(Ag, Bg, lda, ldb, As[0], Bs[0], wid, k_lo << 6);
    __syncthreads();

    for (int kt = k_lo; kt < k_hi; ++kt) {
        if (kt + 1 < k_hi)
            stage_tile(Ag, Bg, lda, ldb, As[cur ^ 1], Bs[cur ^ 1], wid, (kt + 1) << 6);
        const __half* Asb = As[cur];
        const __half* Bsb = Bs[cur];
#pragma unroll
        for (int kk = 0; kk < 2; ++kk) {
            const int ko = kk * 32 + ((lane >> 4) << 3);
            f16x8 af[4], bf[4];
#pragma unroll
            for (int m = 0; m < 4; ++m)
                af[m] = *(const f16x8*)(&Asb[(wr + m * 16 + (lane & 15)) * 64 + ko]);
#pragma unroll
            for (int n = 0; n < 4; ++n)
                bf[n] = *(const f16x8*)(&Bsb[(wc + n * 16 + (lane & 15)) * 64 + ko]);
#pragma unroll
            for (int m = 0; m < 4; ++m)
#pragma unroll
                for (int n = 0; n < 4; ++n)
                    acc[m][n] = __builtin_amdgcn_mfma_f32_16x16x32_f16(af[m], bf[n], acc[m][n], 0, 0, 0);
        }
        __syncthreads();
        cur ^= 1;
    }

    CT* Ct = C;
    if (SPLITK && c > 0) Ct = (CT*)(c == 1 ? P1 : (c == 2 ? P2 : P3));

    const int r0 = (lane >> 4) << 2;
    const int cc = lane & 15;
#pragma unroll
    for (int m = 0; m < 4; ++m) {
#pragma unroll
        for (int n = 0; n < 4; ++n) {
            int col = bcol + wc + n * 16 + cc;
#pragma unroll
            for (int r = 0; r < 4; ++r) {
                int row = brow + wr + m * 16 + r0 + r;
                storeC(Ct, (size_t)row * ldc + col, acc[m][n][r] * scale);
            }
        }
    }
}

// ---------- split-K reduce: out[row] += P1 (+P2 if row>=2048) (+P3 if row>=3072) ----------
__global__ __launch_bounds__(256) void pv_reduce_k(float* __restrict__ out,
                                                   const float* __restrict__ P1,
                                                   const float* __restrict__ P2,
                                                   const float* __restrict__ P3) {
    const int row = 1024 + blockIdx.x;
    const size_t o = (size_t)row * 1024 + threadIdx.x * 4;
    float4 s = *(float4*)(out + o);
    float4 a = *(const float4*)(P1 + o);
    s.x += a.x; s.y += a.y; s.z += a.z; s.w += a.w;
    if (row >= 2048) {
        float4 b = *(const float4*)(P2 + o);
        s.x += b.x; s.y += b.y; s.z += b.z; s.w += b.w;
    }
    if (row >= 3072) {
        float4 d = *(const float4*)(P3 + o);
        s.x += d.x; s.y += d.y; s.z += d.z; s.w += d.w;
    }
    *(float4*)(out + o) = s;
}

// ---------- threefry2x32, JAX PARTITIONABLE variant ----------
__device__ __forceinline__ uint32_t rotl32(uint32_t x, int d) { return (x << d) | (x >> (32 - d)); }

__device__ __forceinline__ bool keep_bit(uint32_t i, uint32_t j) {
    uint32_t x0 = 0u;
    uint32_t x1 = i * 4096u + j;
    const uint32_t ks0 = 0u, ks1 = 42u, ks2 = 0u ^ 42u ^ 0x1BD11BDAu;
    x0 += ks0; x1 += ks1;
#define TFR(r) { x0 += x1; x1 = rotl32(x1, r); x1 ^= x0; }
    TFR(13) TFR(15) TFR(26) TFR(6)   x0 += ks1; x1 += ks2 + 1u;
    TFR(17) TFR(29) TFR(16) TFR(24)  x0 += ks2; x1 += ks0 + 2u;
    TFR(13) TFR(15) TFR(26) TFR(6)   x0 += ks0; x1 += ks1 + 3u;
    TFR(17) TFR(29) TFR(16) TFR(24)  x0 += ks1; x1 += ks2 + 4u;
    TFR(13) TFR(15) TFR(26) TFR(6)   x0 += ks2; x1 += ks0 + 5u;
#undef TFR
    uint32_t bits = x0 ^ x1;
    float u = __uint_as_float((bits >> 9) | 0x3f800000u) - 1.0f;
    return u < 0.9f;
}

// ---------- row softmax + dropout, in-place S(f16) -> P(f16) ----------
__global__ __launch_bounds__(256) void softmax_dropout_k(__half* __restrict__ SP, int N) {
    const int i = blockIdx.x;
    const int tid = threadIdx.x;
    const int len = i + 1;
    __half* row = SP + (size_t)i * N;

    float m = -1.0e30f, l = 0.f;
    const int len8 = len & ~7;
    for (int j = tid * 8; j < len8; j += 2048) {
        int4 pk = *(const int4*)(row + j);
        const __half2* h2 = (const __half2*)&pk;
#pragma unroll
        for (int q = 0; q < 4; ++q) {
            float2 f2 = __half22float2(h2[q]);
            float nm = fmaxf(m, fmaxf(f2.x, f2.y));
            l = l * __expf(m - nm) + __expf(f2.x - nm) + __expf(f2.y - nm);
            m = nm;
        }
    }
    for (int j = len8 + tid; j < len; j += 256) {
        float s = __half2float(row[j]);
        float nm = fmaxf(m, s);
        l = l * __expf(m - nm) + __expf(s - nm);
        m = nm;
    }
    for (int off = 1; off < 64; off <<= 1) {
        float m2 = __shfl_xor(m, off);
        float l2 = __shfl_xor(l, off);
        float nm = fmaxf(m, m2);
        l = l * __expf(m - nm) + l2 * __expf(m2 - nm);
        m = nm;
    }
    __shared__ float ms[4], ls[4];
    if ((tid & 63) == 0) { ms[tid >> 6] = m; ls[tid >> 6] = l; }
    __syncthreads();
    float M = ms[0], L = ls[0];
#pragma unroll
    for (int w = 1; w < 4; ++w) {
        float nm = fmaxf(M, ms[w]);
        L = L * __expf(M - nm) + ls[w] * __expf(ms[w] - nm);
        M = nm;
    }
    const float inv = 1.0f / (L * 0.9f);

    for (int j = tid; j < len; j += 256) {
        float s = __half2float(row[j]);
        float w = __expf(s - M) * inv;
        row[j] = keep_bit((uint32_t)i, (uint32_t)j) ? __float2half(w) : __float2half(0.0f);
    }
    // zero only the diagonal band up to the next 128 boundary (PV reads no further)
    const int zlim = ((i >> 7) << 7) + 128;
    for (int j = len + tid; j < zlim; j += 256) row[j] = __float2half(0.0f);
}

// ---------- launch ----------
extern "C" void kernel_launch(void* const* d_in, const int* in_sizes, int n_in,
                              void* d_out, int out_size, void* d_ws, size_t ws_size,
                              hipStream_t stream) {
    const float* x  = (const float*)d_in[0];
    const float* wq = (const float*)d_in[1];
    const float* wk = (const float*)d_in[2];
    const float* wv = (const float*)d_in[3];
    float* out = (float*)d_out;
    char* ws = (char*)d_ws;

    const int N = 4096, D = 1024;

    __half* xb   = (__half*)(ws + 0);         // 4096x1024   (8 MB)
    __half* wqkv = (__half*)(ws + 8388608);   // 3072x1024   (6 MB)
    __half* QKV  = (__half*)(ws + 14680064);  // 4096x3072   (24 MB), ld=3072
    __half* VT   = (__half*)(ws + 39845888);  // 1024x4096   (8 MB)
    __half* SP   = (__half*)(ws + 48234496);  // 4096x4096   (32 MB), end 81788928

    // split-K partials overlay the (dead-by-then) QKV region:
    // P1 rows 1024..4095 (12MB), P2 rows 2048..4095 (8MB), P3 rows 3072..4095 (4MB)
    float* P1 = (float*)(ws + 14680064) - (size_t)1024 * 1024;
    float* P2 = (float*)(ws + 14680064 + 12582912) - (size_t)2048 * 1024;
    float* P3 = (float*)(ws + 14680064 + 20971520) - (size_t)3072 * 1024;

    __half* Q = QKV;            // lda = 3072
    __half* K = QKV + 1024;
    __half* V = QKV + 2048;

    cast_f32_f16_k<<<2048, 256, 0, stream>>>(x,  xb,  N * D);
    cast_f32_f16_k<<<512,  256, 0, stream>>>(wq, wqkv,             D * D);
    cast_f32_f16_k<<<512,  256, 0, stream>>>(wk, wqkv + D * D,     D * D);
    cast_f32_f16_k<<<512,  256, 0, stream>>>(wv, wqkv + 2 * D * D, D * D);

    // fused QKV projection: [4096x1024] @ [3072x1024]^T -> [4096x3072]
    dim3 gq(N / 128, 3 * D / 128);
    gemm_nt<__half, false, false><<<gq, 256, 0, stream>>>(xb, wqkv, QKV, nullptr, nullptr, nullptr,
                                                          D, D, D, 3 * D, 1.0f);

    dim3 gt(N / 64, D / 64);
    transpose_f16_k<<<gt, 256, 0, stream>>>(V, VT, N, 3 * D);

    dim3 gs(N / 128, N / 128);      // lower-only
    gemm_nt<__half, true, false><<<gs, 256, 0, stream>>>(Q, K, SP, nullptr, nullptr, nullptr,
                                                         D, 3 * D, 3 * D, N, 0.03125f);

    softmax_dropout_k<<<N, 256, 0, stream>>>(SP, N);

    // PV: balanced causal split-K (chunks of <=16 K-iters), then reduce
    dim3 go(80, D / 128);
    gemm_nt<float, false, true><<<go, 256, 0, stream>>>(SP, VT, out, P1, P2, P3,
                                                        N, N, N, D, 1.0f);
    pv_reduce_k<<<3072, 256, 0, stream>>>(out, P1, P2, P3);
}

// Round 6
// 172.023 us; speedup vs baseline: 1.4424x; 1.1926x over previous
//
#include <hip/hip_runtime.h>
#include <hip/hip_fp16.h>

// ---------- types ----------
typedef __attribute__((ext_vector_type(8))) _Float16 f16x8;
typedef __attribute__((ext_vector_type(4))) float f32x4;

typedef const __attribute__((address_space(1))) void gas_void;
typedef __attribute__((address_space(3))) void las_void;
typedef __attribute__((address_space(3))) const __half las_chalf;

// asm ds_read_b128: opaque to the compiler's waitcnt pass (we manage lgkmcnt)
__device__ __forceinline__ f16x8 ldsr(const __half* p) {
    f16x8 r;
    asm volatile("ds_read_b128 %0, %1" : "=v"(r) : "v"((las_chalf*)p));
    return r;
}

// ---------- cast f32 -> f16 ----------
__global__ __launch_bounds__(256) void cast_f32_f16_k(const float* __restrict__ in,
                                                      __half* __restrict__ out, int n) {
    int i = (blockIdx.x * 256 + threadIdx.x) * 8;
    if (i >= n) return;
    float4 a = *(const float4*)(in + i);
    float4 b = *(const float4*)(in + i + 4);
    __half2 h[4] = { __floats2half2_rn(a.x, a.y), __floats2half2_rn(a.z, a.w),
                     __floats2half2_rn(b.x, b.y), __floats2half2_rn(b.z, b.w) };
    *(int4*)(out + i) = *(int4*)h;
}

// ---------- transpose [R][C] (row stride ldin) -> [C][R] (f16) ----------
__global__ __launch_bounds__(256) void transpose_f16_k(const __half* __restrict__ in,
                                                       __half* __restrict__ out,
                                                       int R, int ldin) {
    __shared__ __half t[64][72];
    int r0 = blockIdx.x * 64, c0 = blockIdx.y * 64;
    for (int idx = threadIdx.x; idx < 64 * 64; idx += 256) {
        int r = idx >> 6, c = idx & 63;
        t[r][c] = in[(size_t)(r0 + r) * ldin + c0 + c];
    }
    __syncthreads();
    for (int idx = threadIdx.x; idx < 64 * 64; idx += 256) {
        int r = idx >> 6, c = idx & 63;
        out[(size_t)(c0 + r) * R + r0 + c] = t[c][r];
    }
}

__device__ __forceinline__ void storeC(__half* C, size_t off, float v) { C[off] = __float2half(v); }
__device__ __forceinline__ void storeC(float*  C, size_t off, float v) { C[off] = v; }

// ============================================================================
// 256x256 8-phase GEMM (T2+T3+T4+T5), C = scale * A @ B^T (NT layout, f16).
// 8 waves (2M x 4N), BK=64, LDS 128KB dynamic: [buf(2)][mat(2)][256][64] f16.
// Per K-tile: 4 phases x 16 MFMA. One half-tile (128x64) staged per phase,
// stream runs 6 halves ahead; vmcnt(4) once per K-tile (0 on last tile).
// Swizzle (rule 21): linear LDS dest; source col = ((l&7)^((l>>3)&7))*8;
// read col = ko ^ ((lane&7)<<3). All per-lane constants.
// ============================================================================
template <typename CT, bool LOWER_ONLY>
__global__ __launch_bounds__(512, 2)
void gemm256(const __half* __restrict__ A, const __half* __restrict__ B, CT* __restrict__ C,
             int lda, int ldb, int ldc, int NT, float scale) {
    const int bi = blockIdx.x, bj = blockIdx.y;
    if (LOWER_ONLY && bj > bi) return;
    const int brow = bi * 256, bcol = bj * 256;
    const int tid = threadIdx.x;
    const int lane = tid & 63, wid = tid >> 6;
    const int wm = wid >> 2, wn = wid & 3;
    const int lane15 = lane & 15;
    const int kxor = (lane & 7) << 3;
    const int g16 = (lane >> 4) << 3;

    extern __shared__ __half smem[];  // [2][2][256*64]

    // staging geometry: wave covers 8 rows per gload (2 gloads -> 128-row half)
    const int srow = (wid << 3) + (lane >> 3);                 // 0..63
    const int scol = ((lane & 7) ^ ((lane >> 3) & 7)) << 3;    // swizzled source col (halves)

    // stage one 128x64 half-tile of matrix mat (0=A,1=B) for k-tile kt into buf
    auto stage_half = [&](const __half* G, int ldg, int growbase, int kt, int buf, int mat, int half) {
        const __half* src = G + (size_t)(growbase + half * 128 + srow) * ldg + kt * 64 + scol;
        __half* dst = &smem[buf * 32768 + mat * 16384 + (half * 128 + (wid << 3)) * 64];
        __builtin_amdgcn_global_load_lds((gas_void*)src, (las_void*)dst, 16, 0, 0);
        __builtin_amdgcn_global_load_lds((gas_void*)(src + (size_t)64 * ldg),
                                         (las_void*)(dst + 64 * 64), 16, 0, 0);
    };

    f32x4 acc[8][4] = {};
    f16x8 bfrag[2][4];

    // prologue: tile0 {Ba,Bb,Aa,Ab} + tile1 {Ba,Bb}  (6 halves, 12 loads in flight)
    stage_half(B, ldb, bcol, 0, 0, 1, 0);
    stage_half(B, ldb, bcol, 0, 0, 1, 1);
    stage_half(A, lda, brow, 0, 0, 0, 0);
    stage_half(A, lda, brow, 0, 0, 0, 1);
    if (NT > 1) {
        stage_half(B, ldb, bcol, 1, 1, 1, 0);
        stage_half(B, ldb, bcol, 1, 1, 1, 1);
    }

    for (int T = 0; T < NT; ++T) {
        const int buf = T & 1;
        const __half* Abase = &smem[buf * 32768 + (wm * 128 + lane15) * 64];
        const __half* Bbase = &smem[buf * 32768 + 16384 + (wn * 64 + lane15) * 64];

        // ---- phase 0 ----
        if (T < NT - 1) asm volatile("s_waitcnt vmcnt(4)" ::: "memory");
        else            asm volatile("s_waitcnt vmcnt(0)" ::: "memory");
        __builtin_amdgcn_s_barrier();   // tile T fully resident for all waves

        {
#pragma unroll
            for (int kk = 0; kk < 2; ++kk)
#pragma unroll
                for (int n = 0; n < 4; ++n)
                    bfrag[kk][n] = ldsr(Bbase + (n * 16) * 64 + ((kk * 32 + g16) ^ kxor));
            f16x8 af[2][2];
#pragma unroll
            for (int mi = 0; mi < 2; ++mi)
#pragma unroll
                for (int kk = 0; kk < 2; ++kk)
                    af[mi][kk] = ldsr(Abase + (mi * 16) * 64 + ((kk * 32 + g16) ^ kxor));
            if (T + 1 < NT) stage_half(A, lda, brow, T + 1, (T + 1) & 1, 0, 0);
            asm volatile("s_waitcnt lgkmcnt(0)" ::: "memory");
            __builtin_amdgcn_sched_barrier(0);
            __builtin_amdgcn_s_setprio(1);
#pragma unroll
            for (int mi = 0; mi < 2; ++mi)
#pragma unroll
                for (int n = 0; n < 4; ++n)
#pragma unroll
                    for (int kk = 0; kk < 2; ++kk)
                        acc[mi][n] = __builtin_amdgcn_mfma_f32_16x16x32_f16(
                            af[mi][kk], bfrag[kk][n], acc[mi][n], 0, 0, 0);
            __builtin_amdgcn_s_setprio(0);
            __builtin_amdgcn_s_barrier();
        }

        // ---- phases 1..3 ----
#pragma unroll
        for (int p = 1; p < 4; ++p) {
            f16x8 af[2][2];
#pragma unroll
            for (int mi = 0; mi < 2; ++mi)
#pragma unroll
                for (int kk = 0; kk < 2; ++kk)
                    af[mi][kk] = ldsr(Abase + ((2 * p + mi) * 16) * 64 + ((kk * 32 + g16) ^ kxor));
            if (p == 1)      { if (T + 1 < NT) stage_half(A, lda, brow, T + 1, (T + 1) & 1, 0, 1); }
            else if (p == 2) { if (T + 2 < NT) stage_half(B, ldb, bcol, T + 2, T & 1, 1, 0); }
            else             { if (T + 2 < NT) stage_half(B, ldb, bcol, T + 2, T & 1, 1, 1); }
            asm volatile("s_waitcnt lgkmcnt(0)" ::: "memory");
            __builtin_amdgcn_sched_barrier(0);
            __builtin_amdgcn_s_setprio(1);
#pragma unroll
            for (int mi = 0; mi < 2; ++mi)
#pragma unroll
                for (int n = 0; n < 4; ++n)
#pragma unroll
                    for (int kk = 0; kk < 2; ++kk)
                        acc[2 * p + mi][n] = __builtin_amdgcn_mfma_f32_16x16x32_f16(
                            af[mi][kk], bfrag[kk][n], acc[2 * p + mi][n], 0, 0, 0);
            __builtin_amdgcn_s_setprio(0);
            __builtin_amdgcn_s_barrier();
        }
    }

    // ---- epilogue ----
    const int r0 = (lane >> 4) << 2;
#pragma unroll
    for (int m = 0; m < 8; ++m) {
#pragma unroll
        for (int n = 0; n < 4; ++n) {
            int col = bcol + wn * 64 + n * 16 + lane15;
#pragma unroll
            for (int r = 0; r < 4; ++r) {
                int row = brow + wm * 128 + m * 16 + r0 + r;
                storeC(C, (size_t)row * ldc + col, acc[m][n][r] * scale);
            }
        }
    }
}

// ============================================================================
// 128x128 dbuf GEMM (round-5, proven) — used for PV with balanced causal split-K
// ============================================================================
__device__ __forceinline__ void stage_tile(const __half* Ag, const __half* Bg, int lda, int ldb,
                                           __half* As, __half* Bs, int wid, int k0) {
#pragma unroll
    for (int it = 0; it < 4; ++it) {
        __builtin_amdgcn_global_load_lds(
            (gas_void*)(Ag + (size_t)it * 8 * lda + k0),
            (las_void*)(&As[((wid << 5) + it * 8) * 64]), 16, 0, 0);
        __builtin_amdgcn_global_load_lds(
            (gas_void*)(Bg + (size_t)it * 8 * ldb + k0),
            (las_void*)(&Bs[((wid << 5) + it * 8) * 64]), 16, 0, 0);
    }
}

__global__ __launch_bounds__(256)
void gemm_pv(const __half* __restrict__ A, const __half* __restrict__ B, float* __restrict__ C,
             float* __restrict__ P1, float* __restrict__ P2, float* __restrict__ P3,
             int lda, int ldb, int ldc) {
    int bi, c;
    const int bj = blockIdx.y;
    {
        int x = blockIdx.x;
        if (x < 8)       { bi = x;                    c = 0; }
        else if (x < 24) { bi = 8  + ((x - 8) >> 1);  c = (x - 8) & 1; }
        else if (x < 48) { bi = 16 + (x - 24) / 3;    c = (x - 24) % 3; }
        else             { bi = 24 + ((x - 48) >> 2); c = (x - 48) & 3; }
    }
    const int brow = bi * 128, bcol = bj * 128;
    const int tid = threadIdx.x, lane = tid & 63, wid = tid >> 6;
    const int wr = (wid >> 1) * 64, wc = (wid & 1) * 64;

    const int full = 2 * (bi + 1);
    const int k_lo = c * 16, k_hi = min(full, k_lo + 16);

    __shared__ __align__(16) __half As[2][128 * 64];
    __shared__ __align__(16) __half Bs[2][128 * 64];

    f32x4 acc[4][4] = {};

    const int srow = (wid << 5) + (lane >> 3);
    const int skc  = (lane & 7) << 3;
    const __half* Ag = A + (size_t)(brow + srow) * lda + skc;
    const __half* Bg = B + (size_t)(bcol + srow) * ldb + skc;

    int cur = 0;
    stage_tile(Ag, Bg, lda, ldb, As[0], Bs[0], wid, k_lo << 6);
    __syncthreads();

    for (int kt = k_lo; kt < k_hi; ++kt) {
        if (kt + 1 < k_hi)
            stage_tile(Ag, Bg, lda, ldb, As[cur ^ 1], Bs[cur ^ 1], wid, (kt + 1) << 6);
        const __half* Asb = As[cur];
        const __half* Bsb = Bs[cur];
#pragma unroll
        for (int kk = 0; kk < 2; ++kk) {
            const int ko = kk * 32 + ((lane >> 4) << 3);
            f16x8 af[4], bf[4];
#pragma unroll
            for (int m = 0; m < 4; ++m)
                af[m] = *(const f16x8*)(&Asb[(wr + m * 16 + (lane & 15)) * 64 + ko]);
#pragma unroll
            for (int n = 0; n < 4; ++n)
                bf[n] = *(const f16x8*)(&Bsb[(wc + n * 16 + (lane & 15)) * 64 + ko]);
#pragma unroll
            for (int m = 0; m < 4; ++m)
#pragma unroll
                for (int n = 0; n < 4; ++n)
                    acc[m][n] = __builtin_amdgcn_mfma_f32_16x16x32_f16(af[m], bf[n], acc[m][n], 0, 0, 0);
        }
        __syncthreads();
        cur ^= 1;
    }

    float* Ct = C;
    if (c == 1) Ct = P1; else if (c == 2) Ct = P2; else if (c == 3) Ct = P3;

    const int r0 = (lane >> 4) << 2;
    const int cc = lane & 15;
#pragma unroll
    for (int m = 0; m < 4; ++m) {
#pragma unroll
        for (int n = 0; n < 4; ++n) {
            int col = bcol + wc + n * 16 + cc;
#pragma unroll
            for (int r = 0; r < 4; ++r) {
                int row = brow + wr + m * 16 + r0 + r;
                Ct[(size_t)row * ldc + col] = acc[m][n][r];
            }
        }
    }
}

// ---------- split-K reduce ----------
__global__ __launch_bounds__(256) void pv_reduce_k(float* __restrict__ out,
                                                   const float* __restrict__ P1,
                                                   const float* __restrict__ P2,
                                                   const float* __restrict__ P3) {
    const int row = 1024 + blockIdx.x;
    const size_t o = (size_t)row * 1024 + threadIdx.x * 4;
    float4 s = *(float4*)(out + o);
    float4 a = *(const float4*)(P1 + o);
    s.x += a.x; s.y += a.y; s.z += a.z; s.w += a.w;
    if (row >= 2048) {
        float4 b = *(const float4*)(P2 + o);
        s.x += b.x; s.y += b.y; s.z += b.z; s.w += b.w;
    }
    if (row >= 3072) {
        float4 d = *(const float4*)(P3 + o);
        s.x += d.x; s.y += d.y; s.z += d.z; s.w += d.w;
    }
    *(float4*)(out + o) = s;
}

// ---------- threefry2x32, JAX PARTITIONABLE variant ----------
__device__ __forceinline__ uint32_t rotl32(uint32_t x, int d) { return (x << d) | (x >> (32 - d)); }

__device__ __forceinline__ bool keep_bit(uint32_t i, uint32_t j) {
    uint32_t x0 = 0u;
    uint32_t x1 = i * 4096u + j;
    const uint32_t ks0 = 0u, ks1 = 42u, ks2 = 0u ^ 42u ^ 0x1BD11BDAu;
    x0 += ks0; x1 += ks1;
#define TFR(r) { x0 += x1; x1 = rotl32(x1, r); x1 ^= x0; }
    TFR(13) TFR(15) TFR(26) TFR(6)   x0 += ks1; x1 += ks2 + 1u;
    TFR(17) TFR(29) TFR(16) TFR(24)  x0 += ks2; x1 += ks0 + 2u;
    TFR(13) TFR(15) TFR(26) TFR(6)   x0 += ks0; x1 += ks1 + 3u;
    TFR(17) TFR(29) TFR(16) TFR(24)  x0 += ks1; x1 += ks2 + 4u;
    TFR(13) TFR(15) TFR(26) TFR(6)   x0 += ks2; x1 += ks0 + 5u;
#undef TFR
    uint32_t bits = x0 ^ x1;
    float u = __uint_as_float((bits >> 9) | 0x3f800000u) - 1.0f;
    return u < 0.9f;
}

// ---------- row softmax + dropout, in-place S(f16) -> P(f16) ----------
__global__ __launch_bounds__(256) void softmax_dropout_k(__half* __restrict__ SP, int N) {
    const int i = blockIdx.x;
    const int tid = threadIdx.x;
    const int len = i + 1;
    __half* row = SP + (size_t)i * N;

    float m = -1.0e30f, l = 0.f;
    const int len8 = len & ~7;
    for (int j = tid * 8; j < len8; j += 2048) {
        int4 pk = *(const int4*)(row + j);
        const __half2* h2 = (const __half2*)&pk;
#pragma unroll
        for (int q = 0; q < 4; ++q) {
            float2 f2 = __half22float2(h2[q]);
            float nm = fmaxf(m, fmaxf(f2.x, f2.y));
            l = l * __expf(m - nm) + __expf(f2.x - nm) + __expf(f2.y - nm);
            m = nm;
        }
    }
    for (int j = len8 + tid; j < len; j += 256) {
        float s = __half2float(row[j]);
        float nm = fmaxf(m, s);
        l = l * __expf(m - nm) + __expf(s - nm);
        m = nm;
    }
    for (int off = 1; off < 64; off <<= 1) {
        float m2 = __shfl_xor(m, off);
        float l2 = __shfl_xor(l, off);
        float nm = fmaxf(m, m2);
        l = l * __expf(m - nm) + l2 * __expf(m2 - nm);
        m = nm;
    }
    __shared__ float ms[4], ls[4];
    if ((tid & 63) == 0) { ms[tid >> 6] = m; ls[tid >> 6] = l; }
    __syncthreads();
    float M = ms[0], L = ls[0];
#pragma unroll
    for (int w = 1; w < 4; ++w) {
        float nm = fmaxf(M, ms[w]);
        L = L * __expf(M - nm) + ls[w] * __expf(ms[w] - nm);
        M = nm;
    }
    const float inv = 1.0f / (L * 0.9f);

    for (int j = tid; j < len; j += 256) {
        float s = __half2float(row[j]);
        float w = __expf(s - M) * inv;
        row[j] = keep_bit((uint32_t)i, (uint32_t)j) ? __float2half(w) : __float2half(0.0f);
    }
    // zero the diagonal band up to the next 128 boundary (PV reads no further)
    const int zlim = ((i >> 7) << 7) + 128;
    for (int j = len + tid; j < zlim; j += 256) row[j] = __float2half(0.0f);
}

// ---------- launch ----------
extern "C" void kernel_launch(void* const* d_in, const int* in_sizes, int n_in,
                              void* d_out, int out_size, void* d_ws, size_t ws_size,
                              hipStream_t stream) {
    const float* x  = (const float*)d_in[0];
    const float* wq = (const float*)d_in[1];
    const float* wk = (const float*)d_in[2];
    const float* wv = (const float*)d_in[3];
    float* out = (float*)d_out;
    char* ws = (char*)d_ws;

    const int N = 4096, D = 1024;

    __half* xb   = (__half*)(ws + 0);         // 4096x1024   (8 MB)
    __half* wqkv = (__half*)(ws + 8388608);   // 3072x1024   (6 MB)
    __half* QKV  = (__half*)(ws + 14680064);  // 4096x3072   (24 MB), ld=3072
    __half* VT   = (__half*)(ws + 39845888);  // 1024x4096   (8 MB)
    __half* SP   = (__half*)(ws + 48234496);  // 4096x4096   (32 MB), end 81788928

    float* P1 = (float*)(ws + 14680064) - (size_t)1024 * 1024;
    float* P2 = (float*)(ws + 14680064 + 12582912) - (size_t)2048 * 1024;
    float* P3 = (float*)(ws + 14680064 + 20971520) - (size_t)3072 * 1024;

    __half* Q = QKV;            // lda = 3072
    __half* K = QKV + 1024;
    __half* V = QKV + 2048;

    auto* gqkv_f = gemm256<__half, false>;
    auto* gs_f   = gemm256<__half, true>;
    (void)hipFuncSetAttribute((const void*)gqkv_f, hipFuncAttributeMaxDynamicSharedMemorySize, 131072);
    (void)hipFuncSetAttribute((const void*)gs_f,   hipFuncAttributeMaxDynamicSharedMemorySize, 131072);

    cast_f32_f16_k<<<2048, 256, 0, stream>>>(x,  xb,  N * D);
    cast_f32_f16_k<<<512,  256, 0, stream>>>(wq, wqkv,             D * D);
    cast_f32_f16_k<<<512,  256, 0, stream>>>(wk, wqkv + D * D,     D * D);
    cast_f32_f16_k<<<512,  256, 0, stream>>>(wv, wqkv + 2 * D * D, D * D);

    // fused QKV projection: [4096x1024] @ [3072x1024]^T -> [4096x3072]
    dim3 gq(N / 256, 3 * D / 256);   // 16 x 12
    gqkv_f<<<gq, 512, 131072, stream>>>(xb, wqkv, QKV, D, D, 3 * D, D / 64, 1.0f);

    dim3 gt(N / 64, D / 64);
    transpose_f16_k<<<gt, 256, 0, stream>>>(V, VT, N, 3 * D);

    // S = Q @ K^T * (1/32), lower-triangle blocks only
    dim3 gsd(N / 256, N / 256);      // 16 x 16, bj>bi early-out
    gs_f<<<gsd, 512, 131072, stream>>>(Q, K, SP, 3 * D, 3 * D, N, D / 64, 0.03125f);

    softmax_dropout_k<<<N, 256, 0, stream>>>(SP, N);

    // PV: balanced causal split-K (chunks of <=16 K-iters), then reduce
    dim3 go(80, D / 128);
    gemm_pv<<<go, 256, 0, stream>>>(SP, VT, out, P1, P2, P3, N, N, D);
    pv_reduce_k<<<3072, 256, 0, stream>>>(out, P1, P2, P3);
}

// Round 7
// 154.514 us; speedup vs baseline: 1.6059x; 1.1133x over previous
//
#include <hip/hip_runtime.h>
#include <hip/hip_fp16.h>

// ---------- types ----------
typedef __attribute__((ext_vector_type(8))) _Float16 f16x8;
typedef __attribute__((ext_vector_type(4))) float f32x4;

typedef const __attribute__((address_space(1))) void gas_void;
typedef __attribute__((address_space(3))) void las_void;
typedef __attribute__((address_space(3))) const __half las_chalf;

// asm ds_read_b128: opaque to the compiler's waitcnt pass (we manage lgkmcnt)
__device__ __forceinline__ f16x8 ldsr(const __half* p) {
    f16x8 r;
    asm volatile("ds_read_b128 %0, %1" : "=v"(r) : "v"((las_chalf*)p));
    return r;
}

// ---------- cast f32 -> f16 ----------
__global__ __launch_bounds__(256) void cast_f32_f16_k(const float* __restrict__ in,
                                                      __half* __restrict__ out, int n) {
    int i = (blockIdx.x * 256 + threadIdx.x) * 8;
    if (i >= n) return;
    float4 a = *(const float4*)(in + i);
    float4 b = *(const float4*)(in + i + 4);
    __half2 h[4] = { __floats2half2_rn(a.x, a.y), __floats2half2_rn(a.z, a.w),
                     __floats2half2_rn(b.x, b.y), __floats2half2_rn(b.z, b.w) };
    *(int4*)(out + i) = *(int4*)h;
}

// three 1024x1024 weight casts in one dispatch (grid 1536)
__global__ __launch_bounds__(256) void cast3_f32_f16_k(const float* __restrict__ a,
                                                       const float* __restrict__ b,
                                                       const float* __restrict__ c,
                                                       __half* __restrict__ out) {
    const int which = blockIdx.x >> 9;
    const float* src = which == 0 ? a : (which == 1 ? b : c);
    const int i = (((blockIdx.x & 511) * 256) + threadIdx.x) * 8;
    float4 va = *(const float4*)(src + i);
    float4 vb = *(const float4*)(src + i + 4);
    __half2 h[4] = { __floats2half2_rn(va.x, va.y), __floats2half2_rn(va.z, va.w),
                     __floats2half2_rn(vb.x, vb.y), __floats2half2_rn(vb.z, vb.w) };
    *(int4*)(out + (size_t)which * 1048576 + i) = *(int4*)h;
}

// ---------- transpose [R][C] (row stride ldin) -> [C][R] (f16) ----------
__global__ __launch_bounds__(256) void transpose_f16_k(const __half* __restrict__ in,
                                                       __half* __restrict__ out,
                                                       int R, int ldin) {
    __shared__ __half t[64][72];
    int r0 = blockIdx.x * 64, c0 = blockIdx.y * 64;
    for (int idx = threadIdx.x; idx < 64 * 64; idx += 256) {
        int r = idx >> 6, c = idx & 63;
        t[r][c] = in[(size_t)(r0 + r) * ldin + c0 + c];
    }
    __syncthreads();
    for (int idx = threadIdx.x; idx < 64 * 64; idx += 256) {
        int r = idx >> 6, c = idx & 63;
        out[(size_t)(c0 + r) * R + r0 + c] = t[c][r];
    }
}

__device__ __forceinline__ void storeC(__half* C, size_t off, float v) { C[off] = __float2half(v); }
__device__ __forceinline__ void storeC(float*  C, size_t off, float v) { C[off] = v; }

// ============================================================================
// 256x256 8-phase GEMM (T2+T3+T4+T5), C = scale * A @ B^T (NT layout, f16).
// 8 waves (2M x 4N), BK=64, LDS 128KB dynamic: [buf(2)][mat(2)][256][64] f16.
// SPLITK=true: grid (40,4), balanced causal split-K for PV: row-block bi has
// 4*(bi+1) BK-tiles, chunks of <=16; chunk 0 -> C, chunks 1..3 -> P1..P3.
// ============================================================================
template <typename CT, bool LOWER_ONLY, bool SPLITK>
__global__ __launch_bounds__(512, 2)
void gemm256(const __half* __restrict__ A, const __half* __restrict__ B, CT* __restrict__ C,
             float* __restrict__ P1, float* __restrict__ P2, float* __restrict__ P3,
             int lda, int ldb, int ldc, int NTin, float scale) {
    int bi, c = 0;
    const int bj = blockIdx.y;
    if (SPLITK) {
        int x = blockIdx.x;
        if (x < 4)       { bi = x;                    c = 0; }
        else if (x < 12) { bi = 4  + ((x - 4) >> 1);  c = (x - 4) & 1; }
        else if (x < 24) { bi = 8  + (x - 12) / 3;    c = (x - 12) % 3; }
        else             { bi = 12 + ((x - 24) >> 2); c = (x - 24) & 3; }
    } else {
        bi = blockIdx.x;
        if (LOWER_ONLY && bj > bi) return;
    }
    const int brow = bi * 256, bcol = bj * 256;
    const int tid = threadIdx.x;
    const int lane = tid & 63, wid = tid >> 6;
    const int wm = wid >> 2, wn = wid & 3;
    const int lane15 = lane & 15;
    const int kxor = (lane & 7) << 3;
    const int g16 = (lane >> 4) << 3;

    int k_lo = 0, NT = NTin;
    if (SPLITK) { int full = 4 * (bi + 1); k_lo = c * 16; NT = min(full - k_lo, 16); }

    extern __shared__ __half smem[];  // [2][2][256*64]

    const int srow = (wid << 3) + (lane >> 3);                 // 0..63
    const int scol = ((lane & 7) ^ ((lane >> 3) & 7)) << 3;    // swizzled source col

    auto stage_half = [&](const __half* G, int ldg, int growbase, int kt, int buf, int mat, int half) {
        const __half* src = G + (size_t)(growbase + half * 128 + srow) * ldg + kt * 64 + scol;
        __half* dst = &smem[buf * 32768 + mat * 16384 + (half * 128 + (wid << 3)) * 64];
        __builtin_amdgcn_global_load_lds((gas_void*)src, (las_void*)dst, 16, 0, 0);
        __builtin_amdgcn_global_load_lds((gas_void*)(src + (size_t)64 * ldg),
                                         (las_void*)(dst + 64 * 64), 16, 0, 0);
    };

    f32x4 acc[8][4] = {};
    f16x8 bfrag[2][4];

    // prologue: tile k_lo {Ba,Bb,Aa,Ab} + tile k_lo+1 {Ba,Bb}
    stage_half(B, ldb, bcol, k_lo, 0, 1, 0);
    stage_half(B, ldb, bcol, k_lo, 0, 1, 1);
    stage_half(A, lda, brow, k_lo, 0, 0, 0);
    stage_half(A, lda, brow, k_lo, 0, 0, 1);
    if (NT > 1) {
        stage_half(B, ldb, bcol, k_lo + 1, 1, 1, 0);
        stage_half(B, ldb, bcol, k_lo + 1, 1, 1, 1);
    }

    for (int Tr = 0; Tr < NT; ++Tr) {
        const int Ta = k_lo + Tr;
        const int buf = Tr & 1;
        const __half* Abase = &smem[buf * 32768 + (wm * 128 + lane15) * 64];
        const __half* Bbase = &smem[buf * 32768 + 16384 + (wn * 64 + lane15) * 64];

        // ---- phase 0 ----
        if (Tr < NT - 1) asm volatile("s_waitcnt vmcnt(4)" ::: "memory");
        else             asm volatile("s_waitcnt vmcnt(0)" ::: "memory");
        __builtin_amdgcn_s_barrier();   // tile Tr fully resident for all waves

        {
#pragma unroll
            for (int kk = 0; kk < 2; ++kk)
#pragma unroll
                for (int n = 0; n < 4; ++n)
                    bfrag[kk][n] = ldsr(Bbase + (n * 16) * 64 + ((kk * 32 + g16) ^ kxor));
            f16x8 af[2][2];
#pragma unroll
            for (int mi = 0; mi < 2; ++mi)
#pragma unroll
                for (int kk = 0; kk < 2; ++kk)
                    af[mi][kk] = ldsr(Abase + (mi * 16) * 64 + ((kk * 32 + g16) ^ kxor));
            if (Tr + 1 < NT) stage_half(A, lda, brow, Ta + 1, buf ^ 1, 0, 0);
            asm volatile("s_waitcnt lgkmcnt(0)" ::: "memory");
            __builtin_amdgcn_sched_barrier(0);
            __builtin_amdgcn_s_setprio(1);
#pragma unroll
            for (int mi = 0; mi < 2; ++mi)
#pragma unroll
                for (int n = 0; n < 4; ++n)
#pragma unroll
                    for (int kk = 0; kk < 2; ++kk)
                        acc[mi][n] = __builtin_amdgcn_mfma_f32_16x16x32_f16(
                            af[mi][kk], bfrag[kk][n], acc[mi][n], 0, 0, 0);
            __builtin_amdgcn_s_setprio(0);
            __builtin_amdgcn_s_barrier();
        }

        // ---- phases 1..3 ----
#pragma unroll
        for (int p = 1; p < 4; ++p) {
            f16x8 af[2][2];
#pragma unroll
            for (int mi = 0; mi < 2; ++mi)
#pragma unroll
                for (int kk = 0; kk < 2; ++kk)
                    af[mi][kk] = ldsr(Abase + ((2 * p + mi) * 16) * 64 + ((kk * 32 + g16) ^ kxor));
            if (p == 1)      { if (Tr + 1 < NT) stage_half(A, lda, brow, Ta + 1, buf ^ 1, 0, 1); }
            else if (p == 2) { if (Tr + 2 < NT) stage_half(B, ldb, bcol, Ta + 2, buf, 1, 0); }
            else             { if (Tr + 2 < NT) stage_half(B, ldb, bcol, Ta + 2, buf, 1, 1); }
            asm volatile("s_waitcnt lgkmcnt(0)" ::: "memory");
            __builtin_amdgcn_sched_barrier(0);
            __builtin_amdgcn_s_setprio(1);
#pragma unroll
            for (int mi = 0; mi < 2; ++mi)
#pragma unroll
                for (int n = 0; n < 4; ++n)
#pragma unroll
                    for (int kk = 0; kk < 2; ++kk)
                        acc[2 * p + mi][n] = __builtin_amdgcn_mfma_f32_16x16x32_f16(
                            af[mi][kk], bfrag[kk][n], acc[2 * p + mi][n], 0, 0, 0);
            __builtin_amdgcn_s_setprio(0);
            __builtin_amdgcn_s_barrier();
        }
    }

    // ---- epilogue ----
    CT* Ct = C;
    if (SPLITK && c > 0) Ct = (CT*)(c == 1 ? P1 : (c == 2 ? P2 : P3));
    const int r0 = (lane >> 4) << 2;
#pragma unroll
    for (int m = 0; m < 8; ++m) {
#pragma unroll
        for (int n = 0; n < 4; ++n) {
            int col = bcol + wn * 64 + n * 16 + lane15;
#pragma unroll
            for (int r = 0; r < 4; ++r) {
                int row = brow + wm * 128 + m * 16 + r0 + r;
                storeC(Ct, (size_t)row * ldc + col, acc[m][n][r] * scale);
            }
        }
    }
}

// ---------- split-K reduce: out[row] += P1 (+P2 if row>=2048) (+P3 if row>=3072) ----------
__global__ __launch_bounds__(256) void pv_reduce_k(float* __restrict__ out,
                                                   const float* __restrict__ P1,
                                                   const float* __restrict__ P2,
                                                   const float* __restrict__ P3) {
    const int row = 1024 + blockIdx.x;
    const size_t o = (size_t)row * 1024 + threadIdx.x * 4;
    float4 s = *(float4*)(out + o);
    float4 a = *(const float4*)(P1 + o);
    s.x += a.x; s.y += a.y; s.z += a.z; s.w += a.w;
    if (row >= 2048) {
        float4 b = *(const float4*)(P2 + o);
        s.x += b.x; s.y += b.y; s.z += b.z; s.w += b.w;
    }
    if (row >= 3072) {
        float4 d = *(const float4*)(P3 + o);
        s.x += d.x; s.y += d.y; s.z += d.z; s.w += d.w;
    }
    *(float4*)(out + o) = s;
}

// ---------- threefry2x32, JAX PARTITIONABLE variant ----------
__device__ __forceinline__ uint32_t rotl32(uint32_t x, int d) { return (x << d) | (x >> (32 - d)); }

__device__ __forceinline__ bool keep_bit(uint32_t i, uint32_t j) {
    uint32_t x0 = 0u;
    uint32_t x1 = i * 4096u + j;
    const uint32_t ks0 = 0u, ks1 = 42u, ks2 = 0u ^ 42u ^ 0x1BD11BDAu;
    x0 += ks0; x1 += ks1;
#define TFR(r) { x0 += x1; x1 = rotl32(x1, r); x1 ^= x0; }
    TFR(13) TFR(15) TFR(26) TFR(6)   x0 += ks1; x1 += ks2 + 1u;
    TFR(17) TFR(29) TFR(16) TFR(24)  x0 += ks2; x1 += ks0 + 2u;
    TFR(13) TFR(15) TFR(26) TFR(6)   x0 += ks0; x1 += ks1 + 3u;
    TFR(17) TFR(29) TFR(16) TFR(24)  x0 += ks1; x1 += ks2 + 4u;
    TFR(13) TFR(15) TFR(26) TFR(6)   x0 += ks2; x1 += ks0 + 5u;
#undef TFR
    uint32_t bits = x0 ^ x1;
    float u = __uint_as_float((bits >> 9) | 0x3f800000u) - 1.0f;
    return u < 0.9f;
}

// ---------- row softmax + dropout, in-place S(f16) -> P(f16) ----------
__global__ __launch_bounds__(256) void softmax_dropout_k(__half* __restrict__ SP, int N) {
    const int i = blockIdx.x;
    const int tid = threadIdx.x;
    const int len = i + 1;
    __half* row = SP + (size_t)i * N;

    float m = -1.0e30f, l = 0.f;
    const int len8 = len & ~7;
    for (int j = tid * 8; j < len8; j += 2048) {
        int4 pk = *(const int4*)(row + j);
        const __half2* h2 = (const __half2*)&pk;
#pragma unroll
        for (int q = 0; q < 4; ++q) {
            float2 f2 = __half22float2(h2[q]);
            float nm = fmaxf(m, fmaxf(f2.x, f2.y));
            l = l * __expf(m - nm) + __expf(f2.x - nm) + __expf(f2.y - nm);
            m = nm;
        }
    }
    for (int j = len8 + tid; j < len; j += 256) {
        float s = __half2float(row[j]);
        float nm = fmaxf(m, s);
        l = l * __expf(m - nm) + __expf(s - nm);
        m = nm;
    }
    for (int off = 1; off < 64; off <<= 1) {
        float m2 = __shfl_xor(m, off);
        float l2 = __shfl_xor(l, off);
        float nm = fmaxf(m, m2);
        l = l * __expf(m - nm) + l2 * __expf(m2 - nm);
        m = nm;
    }
    __shared__ float ms[4], ls[4];
    if ((tid & 63) == 0) { ms[tid >> 6] = m; ls[tid >> 6] = l; }
    __syncthreads();
    float M = ms[0], L = ls[0];
#pragma unroll
    for (int w = 1; w < 4; ++w) {
        float nm = fmaxf(M, ms[w]);
        L = L * __expf(M - nm) + ls[w] * __expf(ms[w] - nm);
        M = nm;
    }
    const float inv = 1.0f / (L * 0.9f);

    for (int j = tid; j < len; j += 256) {
        float s = __half2float(row[j]);
        float w = __expf(s - M) * inv;
        row[j] = keep_bit((uint32_t)i, (uint32_t)j) ? __float2half(w) : __float2half(0.0f);
    }
    // zero the diagonal band up to the next 256 boundary (PV K-tiles are 256 wide)
    const int zlim = ((i >> 8) << 8) + 256;
    for (int j = len + tid; j < zlim; j += 256) row[j] = __float2half(0.0f);
}

// ---------- launch ----------
extern "C" void kernel_launch(void* const* d_in, const int* in_sizes, int n_in,
                              void* d_out, int out_size, void* d_ws, size_t ws_size,
                              hipStream_t stream) {
    const float* x  = (const float*)d_in[0];
    const float* wq = (const float*)d_in[1];
    const float* wk = (const float*)d_in[2];
    const float* wv = (const float*)d_in[3];
    float* out = (float*)d_out;
    char* ws = (char*)d_ws;

    const int N = 4096, D = 1024;

    __half* xb   = (__half*)(ws + 0);         // 4096x1024   (8 MB)
    __half* wqkv = (__half*)(ws + 8388608);   // 3072x1024   (6 MB)
    __half* QKV  = (__half*)(ws + 14680064);  // 4096x3072   (24 MB), ld=3072
    __half* VT   = (__half*)(ws + 39845888);  // 1024x4096   (8 MB)
    __half* SP   = (__half*)(ws + 48234496);  // 4096x4096   (32 MB), end 81788928

    // split-K partials overlay the (dead-by-then) QKV region
    float* P1 = (float*)(ws + 14680064) - (size_t)1024 * 1024;
    float* P2 = (float*)(ws + 14680064 + 12582912) - (size_t)2048 * 1024;
    float* P3 = (float*)(ws + 14680064 + 20971520) - (size_t)3072 * 1024;

    __half* Q = QKV;            // lda = 3072
    __half* K = QKV + 1024;
    __half* V = QKV + 2048;

    auto* gqkv_f = gemm256<__half, false, false>;
    auto* gs_f   = gemm256<__half, true,  false>;
    auto* gpv_f  = gemm256<float,  false, true>;
    (void)hipFuncSetAttribute((const void*)gqkv_f, hipFuncAttributeMaxDynamicSharedMemorySize, 131072);
    (void)hipFuncSetAttribute((const void*)gs_f,   hipFuncAttributeMaxDynamicSharedMemorySize, 131072);
    (void)hipFuncSetAttribute((const void*)gpv_f,  hipFuncAttributeMaxDynamicSharedMemorySize, 131072);

    cast_f32_f16_k<<<2048, 256, 0, stream>>>(x, xb, N * D);
    cast3_f32_f16_k<<<1536, 256, 0, stream>>>(wq, wk, wv, wqkv);

    // fused QKV projection: [4096x1024] @ [3072x1024]^T -> [4096x3072]
    dim3 gq(N / 256, 3 * D / 256);   // 16 x 12
    gqkv_f<<<gq, 512, 131072, stream>>>(xb, wqkv, QKV, nullptr, nullptr, nullptr,
                                        D, D, 3 * D, D / 64, 1.0f);

    dim3 gt(N / 64, D / 64);
    transpose_f16_k<<<gt, 256, 0, stream>>>(V, VT, N, 3 * D);

    // S = Q @ K^T * (1/32), lower-triangle blocks only
    dim3 gsd(N / 256, N / 256);      // 16 x 16, bj>bi early-out
    gs_f<<<gsd, 512, 131072, stream>>>(Q, K, SP, nullptr, nullptr, nullptr,
                                       3 * D, 3 * D, N, D / 64, 0.03125f);

    softmax_dropout_k<<<N, 256, 0, stream>>>(SP, N);

    // PV on the 8-phase engine: balanced causal split-K (chunks of <=16 BK-tiles)
    dim3 go(40, D / 256);            // 160 blocks
    gpv_f<<<go, 512, 131072, stream>>>(SP, VT, out, P1, P2, P3,
                                       N, N, D, 0, 1.0f);
    pv_reduce_k<<<3072, 256, 0, stream>>>(out, P1, P2, P3);
}